// Round 1
// baseline (317.404 us; speedup 1.0000x reference)
//
#include <hip/hip_runtime.h>
#include <hip/hip_bf16.h>

// Problem constants (reference: B=32, S=2048, D=1024, F=512, E=8, GROUP=32 -> 1 group)
#define SS 2048
#define BB 32
#define DD 1024
#define FF 512
#define EE 8

typedef __attribute__((ext_vector_type(8))) short short8;
typedef __attribute__((ext_vector_type(8))) unsigned short ushort8v;
typedef __attribute__((ext_vector_type(4))) float f32x4;

__device__ inline unsigned short f2bf(float f) {
  union { float f; unsigned u; } v; v.f = f;
  return (unsigned short)((v.u + 0x7FFFu + ((v.u >> 16) & 1u)) >> 16);
}
__device__ inline float bf2f(unsigned short h) {
  union { unsigned u; float f; } v; v.u = ((unsigned)h) << 16;
  return v.f;
}

// ---------------- transpose + fp32->bf16 cast: in (E,K,N) f32 -> out (E,N,K) bf16
__global__ __launch_bounds__(256) void transpose_bf16(
    const float* __restrict__ in, unsigned short* __restrict__ out, int K, int N) {
  __shared__ float tile[32][33];
  int e = blockIdx.z;
  const float* inp = in + (size_t)e * K * N;
  unsigned short* outp = out + (size_t)e * K * N;
  int k0 = blockIdx.x * 32, n0 = blockIdx.y * 32;
  int tx = threadIdx.x;   // 0..31
  int ty = threadIdx.y;   // 0..7
#pragma unroll
  for (int i = 0; i < 4; i++) {
    int k = ty + i * 8;
    tile[k][tx] = inp[(size_t)(k0 + k) * N + n0 + tx];
  }
  __syncthreads();
#pragma unroll
  for (int i = 0; i < 4; i++) {
    int n = ty + i * 8;
    outp[(size_t)(n0 + n) * K + k0 + tx] = f2bf(tile[tx][n]);
  }
}

// ---------------- controller logits + softmax over 32 tokens + merged tokens
// one block per s; 256 threads
__global__ __launch_bounds__(256) void ctrl_merge(
    const float* __restrict__ x,          // (B,S,D) f32
    const float* __restrict__ ctrl,       // (D,E) f32
    unsigned short* __restrict__ merged,  // (S,E,D) bf16
    float* __restrict__ mw) {             // (S,B,E) f32
  int s = blockIdx.x;
  int t = threadIdx.x;
  __shared__ float cs[DD * EE];    // 32 KiB controller copy
  __shared__ float lg[BB][EE];     // logits -> weights in place
  for (int i = t; i < DD * EE; i += 256) cs[i] = ctrl[i];
  __syncthreads();

  // phase A: one thread per (k,e) dot product over D
  int k = t >> 3, e = t & 7;
  const float* xr = x + ((size_t)k * SS + s) * DD;
  float acc = 0.f;
  for (int d = 0; d < DD; d += 4) {
    float4 xv = *(const float4*)&xr[d];
    acc += xv.x * cs[d * 8 + e] + xv.y * cs[(d + 1) * 8 + e] +
           xv.z * cs[(d + 2) * 8 + e] + xv.w * cs[(d + 3) * 8 + e];
  }
  lg[k][e] = acc;
  __syncthreads();

  // phase B: softmax over k (tokens) per expert column e = t
  if (t < EE) {
    float m = -1e30f;
    for (int kk = 0; kk < BB; kk++) m = fmaxf(m, lg[kk][t]);
    float sum = 0.f;
    for (int kk = 0; kk < BB; kk++) sum += __expf(lg[kk][t] - m);
    float inv = 1.f / sum;
    for (int kk = 0; kk < BB; kk++) {
      float w = __expf(lg[kk][t] - m) * inv;
      lg[kk][t] = w;
      mw[((size_t)s * BB + kk) * EE + t] = w;
    }
  }
  __syncthreads();

  // phase C: merged[e][d] = sum_k w[k][e] * x[k,s,d]; thread t owns d = j*256+t
  float accm[EE][4];
#pragma unroll
  for (int ee = 0; ee < EE; ee++)
#pragma unroll
    for (int j = 0; j < 4; j++) accm[ee][j] = 0.f;
  for (int kk = 0; kk < BB; kk++) {
    float w0 = lg[kk][0], w1 = lg[kk][1], w2 = lg[kk][2], w3 = lg[kk][3];
    float w4 = lg[kk][4], w5 = lg[kk][5], w6 = lg[kk][6], w7 = lg[kk][7];
#pragma unroll
    for (int j = 0; j < 4; j++) {
      float xv = x[((size_t)kk * SS + s) * DD + j * 256 + t];
      accm[0][j] += w0 * xv; accm[1][j] += w1 * xv;
      accm[2][j] += w2 * xv; accm[3][j] += w3 * xv;
      accm[4][j] += w4 * xv; accm[5][j] += w5 * xv;
      accm[6][j] += w6 * xv; accm[7][j] += w7 * xv;
    }
  }
#pragma unroll
  for (int ee = 0; ee < EE; ee++)
#pragma unroll
    for (int j = 0; j < 4; j++)
      merged[((size_t)s * EE + ee) * DD + j * 256 + t] = f2bf(accm[ee][j]);
}

// ---------------- bf16 MFMA GEMM, B-transposed weights (both operands k-contiguous)
// A: (S, E, K) bf16, expert slice rows stride E*K ; Bt: (E, N, K) bf16 ; C: (S, E, N) bf16
// grid: (S/128, N/128, E), 256 threads = 4 waves (2x2), wave tile 64x64, 16x16x32 frags
template <int RELU>
__global__ __launch_bounds__(256) void gemm_bt(
    const unsigned short* __restrict__ A, const unsigned short* __restrict__ Bt,
    unsigned short* __restrict__ C, int K, int N) {
  int e = blockIdx.z;
  int m0 = blockIdx.x * 128;
  int n0 = blockIdx.y * 128;
  const int lda = EE * K;
  const unsigned short* Ae = A + (size_t)e * K;
  const unsigned short* Be = Bt + (size_t)e * N * K;

  __shared__ __align__(16) unsigned short As[128][40];  // +8 pad: bank-conflict-free b128
  __shared__ __align__(16) unsigned short Bs[128][40];

  int t = threadIdx.x;
  int lane = t & 63, w = t >> 6;
  int wm = w >> 1, wn = w & 1;
  int lr = lane & 15;     // fragment row
  int kh = lane >> 4;     // k-half index: k-offset kh*8

  f32x4 acc[4][4] = {};

  for (int kt = 0; kt < K; kt += 32) {
    // stage A and Bt tiles: 128x32 bf16 each = 512 ushort8 chunks, 2 per thread
#pragma unroll
    for (int i = 0; i < 2; i++) {
      int o = t + i * 256;          // 0..511
      int r = o >> 2, c8 = (o & 3) * 8;
      ushort8v va = *(const ushort8v*)&Ae[(size_t)(m0 + r) * lda + kt + c8];
      *(ushort8v*)&As[r][c8] = va;
      ushort8v vb = *(const ushort8v*)&Be[(size_t)(n0 + r) * K + kt + c8];
      *(ushort8v*)&Bs[r][c8] = vb;
    }
    __syncthreads();

    short8 af[4], bfr[4];
#pragma unroll
    for (int mi = 0; mi < 4; mi++)
      af[mi] = *(const short8*)&As[wm * 64 + mi * 16 + lr][kh * 8];
#pragma unroll
    for (int ni = 0; ni < 4; ni++)
      bfr[ni] = *(const short8*)&Bs[wn * 64 + ni * 16 + lr][kh * 8];
#pragma unroll
    for (int mi = 0; mi < 4; mi++)
#pragma unroll
      for (int ni = 0; ni < 4; ni++)
        acc[mi][ni] = __builtin_amdgcn_mfma_f32_16x16x32_bf16(af[mi], bfr[ni], acc[mi][ni], 0, 0, 0);
    __syncthreads();
  }

  // epilogue: C/D layout col=lane&15, row=(lane>>4)*4+reg  [verified m89]
  int rb = (lane >> 4) * 4;
  int cb = lane & 15;
#pragma unroll
  for (int mi = 0; mi < 4; mi++)
#pragma unroll
    for (int ni = 0; ni < 4; ni++)
#pragma unroll
      for (int r = 0; r < 4; r++) {
        float v = acc[mi][ni][r];
        if (RELU) v = fmaxf(v, 0.f);
        int m = m0 + wm * 64 + mi * 16 + rb + r;
        int n = n0 + wn * 64 + ni * 16 + cb;
        C[(size_t)m * (EE * N) + (size_t)e * N + n] = f2bf(v);
      }
}

// ---------------- emit: out[b,s,d] = sum_e mw[s,b,e] * eo[s,e,d]
__global__ __launch_bounds__(256) void emit_out(
    const unsigned short* __restrict__ eo,  // (S,E,D) bf16
    const float* __restrict__ mw,           // (S,B,E) f32
    float* __restrict__ out) {              // (B,S,D) f32
  int s = blockIdx.x;
  int t = threadIdx.x;
  __shared__ float w[BB][EE];
  w[t >> 3][t & 7] = mw[(size_t)s * BB * EE + t];
  __syncthreads();
  float ev[EE][4];
#pragma unroll
  for (int ee = 0; ee < EE; ee++)
#pragma unroll
    for (int j = 0; j < 4; j++)
      ev[ee][j] = bf2f(eo[((size_t)s * EE + ee) * DD + j * 256 + t]);
  for (int b = 0; b < BB; b++) {
#pragma unroll
    for (int j = 0; j < 4; j++) {
      float acc = 0.f;
#pragma unroll
      for (int ee = 0; ee < EE; ee++) acc += w[b][ee] * ev[ee][j];
      out[((size_t)b * SS + s) * DD + j * 256 + t] = acc;
    }
  }
}

extern "C" void kernel_launch(void* const* d_in, const int* in_sizes, int n_in,
                              void* d_out, int out_size, void* d_ws, size_t ws_size,
                              hipStream_t stream) {
  const float* x = (const float*)d_in[0];        // (32, 2048, 1024)
  const float* lin1 = (const float*)d_in[1];     // (8, 1024, 512)
  const float* lin2 = (const float*)d_in[2];     // (8, 512, 1024)
  const float* ctrl = (const float*)d_in[3];     // (1024, 8)
  float* out = (float*)d_out;

  char* ws = (char*)d_ws;
  size_t off = 0;
  unsigned short* lin1t = (unsigned short*)(ws + off); off += (size_t)EE * DD * FF * 2;  // (E,F,D) 8 MiB
  unsigned short* lin2t = (unsigned short*)(ws + off); off += (size_t)EE * FF * DD * 2;  // (E,D,F) 8 MiB
  unsigned short* merged = (unsigned short*)(ws + off); off += (size_t)SS * EE * DD * 2; // 32 MiB
  unsigned short* hbuf = (unsigned short*)(ws + off); off += (size_t)SS * EE * FF * 2;   // 16 MiB
  unsigned short* eo = (unsigned short*)(ws + off); off += (size_t)SS * EE * DD * 2;     // 32 MiB
  float* mw = (float*)(ws + off); off += (size_t)SS * BB * EE * 4;                       // 2 MiB

  dim3 tb(32, 8);
  // lin1 (E, K=D, N=F) -> lin1t (E, F, D)
  transpose_bf16<<<dim3(DD / 32, FF / 32, EE), tb, 0, stream>>>(lin1, lin1t, DD, FF);
  // lin2 (E, K=F, N=D) -> lin2t (E, D, F)
  transpose_bf16<<<dim3(FF / 32, DD / 32, EE), tb, 0, stream>>>(lin2, lin2t, FF, DD);

  ctrl_merge<<<SS, 256, 0, stream>>>(x, ctrl, merged, mw);

  // h = relu(merged @ lin1): M=S per expert, K=D, N=F
  gemm_bt<1><<<dim3(SS / 128, FF / 128, EE), 256, 0, stream>>>(merged, lin1t, hbuf, DD, FF);
  // eo = h @ lin2: K=F, N=D
  gemm_bt<0><<<dim3(SS / 128, DD / 128, EE), 256, 0, stream>>>(hbuf, lin2t, eo, FF, DD);

  emit_out<<<SS, 256, 0, stream>>>(eo, mw, out);
}